// Round 11
// baseline (37.885 us; speedup 1.0000x reference)
//
#include <hip/hip_runtime.h>
#include <hip/hip_bf16.h>

// R11: MEASUREMENT ROUND. Exact R9 pipeline (best known, 30.6us) with kB
// launched TWICE (idempotent: pure function of Xu/Mt, fully overwrites part).
//   dur(R11) - dur(R9) = kB standalone duration + 1 graph-node overhead.
// Discriminates: ledger says kB~19us; cycle model says ~4us + big fixed overhead.
// Whichever branch holds picks the R12 strategy (kB interior vs node-count).
// Pipeline: kFront (GEMM1 reg-staged + all prep packed) -> kB x2 (GEMM2 64x64
// splitK x8 uneven, BK=64, bf16 partials) -> kC (sum 8 + bias/residual/LN).

typedef __attribute__((ext_vector_type(8))) short bf16x8;
typedef __attribute__((ext_vector_type(4))) float f32x4;
typedef unsigned short ushort_t;

#define LDA_X 2816
#define N_POOL 512
#define D_POOL 4096

__device__ __forceinline__ void gld16(const ushort_t* g, ushort_t* l) {
    __builtin_amdgcn_global_load_lds((__attribute__((address_space(1))) void*)g,
                                     (__attribute__((address_space(3))) void*)l, 16, 0, 0);
}

__device__ __forceinline__ ushort_t bfb(float x) {
    union { __hip_bfloat16 h; ushort_t u; } c; c.h = __float2bfloat16(x); return c.u;
}

__device__ __forceinline__ float bf2f(ushort_t u) {
    union { unsigned int i; float f; } c; c.i = ((unsigned int)u) << 16; return c.f;
}

__device__ __forceinline__ void write4(ushort_t* p, float4 v) {
    ushort4 w = {bfb(v.x), bfb(v.y), bfb(v.z), bfb(v.w)};
    *(ushort4*)p = w;
}

// ================= kFront: GEMM1 (0..1023) + prep (1024..3167) =================
__global__ __launch_bounds__(256) void kFront(const float* __restrict__ hA,
                                              const float* __restrict__ pool,
                                              const float* __restrict__ alpha,
                                              const float* __restrict__ Wb,
                                              ushort_t* __restrict__ Xu,
                                              ushort_t* __restrict__ Mt) {
    __shared__ __align__(16) ushort_t shmem[16384];   // 32KB pool
    ushort_t* As = shmem;                             // [2][4096]
    ushort_t* Bs = shmem + 8192;
    const int t = threadIdx.x;
    const int bid = blockIdx.x;

    if (bid >= 1024) {  // ---------------- prep path ----------------
        const int b2 = bid - 1024;
        if (b2 < 512) {                    // X hA seg [2048][256]
            int idx = b2 * 256 + t, b = idx >> 6, a4 = (idx & 63) << 2;
            write4(Xu + (size_t)b * LDA_X + 2048 + a4, *(const float4*)&hA[(size_t)b * 256 + a4]);
        } else if (b2 < 1536) {            // X alpha seg [2048][512]
            int idx = (b2 - 512) * 256 + t, b = idx >> 7, j4 = (idx & 127) << 2;
            write4(Xu + (size_t)b * LDA_X + 2304 + j4, *(const float4*)&alpha[(size_t)b * 512 + j4]);
        } else if (b2 < 2048) {            // Mt U: [c][4n..] = pool[n][4c..]
            int idx = (b2 - 1536) * 256 + t, c = idx >> 9, n = idx & 511;
            write4(Mt + (size_t)c * LDA_X + (n << 2), *(const float4*)&pool[(size_t)n * D_POOL + (c << 2)]);
        } else if (b2 < 2112) {            // Mt Wb: [c][2048+q]
            int idx = (b2 - 2048) * 256 + t, c = idx >> 6, q = (idx & 63) << 2;
            write4(Mt + (size_t)c * LDA_X + 2048 + q, *(const float4*)&Wb[(size_t)c * 256 + q]);
        } else {                           // Mt bias via 64x64 LDS transpose
            float* Lf = (float*)shmem;     // [64][65] f32 = 16.6KB
            int tb = b2 - 2112;            // 0..31
            int j0 = (tb >> 2) * 64, c0t = (tb & 3) * 64;
            #pragma unroll
            for (int i = 0; i < 16; ++i) {
                int idx = i * 256 + t, jj = idx >> 6, cc = idx & 63;
                Lf[jj * 65 + cc] = pool[(size_t)(j0 + jj) * D_POOL + 2048 + c0t + cc];
            }
            __syncthreads();
            int cc = t >> 2, js = (t & 3) * 16;
            __align__(16) ushort_t u[16];
            #pragma unroll
            for (int j = 0; j < 16; ++j) u[j] = bfb(Lf[(js + j) * 65 + cc]);
            ushort_t* dst = Mt + (size_t)(c0t + cc) * LDA_X + 2304 + j0 + js;
            *(uint4*)dst = ((uint4*)u)[0];
            *(uint4*)(dst + 8) = ((uint4*)u)[1];
        }
        return;
    }

    // ---------------- GEMM1 path (reg-staged, verified) ----------------
    const int w = t >> 6, l = t & 63, l16 = l & 15, l4 = l >> 4;
    const int wr = w >> 1, wc = w & 1;
    const int bm0 = (bid >> 5) * 64, bn0 = (bid & 31) * 64;
    const int row = t >> 2, cs = t & 3;

    f32x4 acc[2][2];
    #pragma unroll
    for (int i = 0; i < 2; ++i)
        #pragma unroll
        for (int j = 0; j < 2; ++j) acc[i][j] = (f32x4){0.f, 0.f, 0.f, 0.f};

    float4 aR[4], bR[4];
    const int kk = bn0 + row;
    const float* bbase = pool + (size_t)(kk >> 2) * D_POOL + 1024 + (kk & 3) * 256;
    const float* abase = hA + (size_t)(bm0 + row) * 256;

    auto loadRegs = [&](int step) {
        const int a0 = step * 64;
        #pragma unroll
        for (int p = 0; p < 4; ++p) {
            int c0 = (cs + p * 4) << 2;
            aR[p] = *(const float4*)(abase + a0 + c0);
            bR[p] = *(const float4*)(bbase + a0 + c0);
        }
    };
    auto writeLDS = [&](int buf) {
        #pragma unroll
        for (int p = 0; p < 4; ++p) {
            int c0 = (cs + p * 4) << 2;
            int off = row * 64 + (((c0 >> 3) ^ (row & 7)) << 3) + ((c0 >> 2) & 1) * 4;
            ushort4 ua = {bfb(aR[p].x), bfb(aR[p].y), bfb(aR[p].z), bfb(aR[p].w)};
            ushort4 ub = {bfb(bR[p].x), bfb(bR[p].y), bfb(bR[p].z), bfb(bR[p].w)};
            *(ushort4*)&As[buf * 4096 + off] = ua;
            *(ushort4*)&Bs[buf * 4096 + off] = ub;
        }
    };
    auto compute = [&](int buf) {
        bf16x8 af[2][2], bv[2][2];
        #pragma unroll
        for (int mi = 0; mi < 2; ++mi) {
            int arow = wr * 32 + mi * 16 + l16;
            #pragma unroll
            for (int ks = 0; ks < 2; ++ks)
                af[mi][ks] = *(const bf16x8*)&As[buf * 4096 + arow * 64 + (((ks * 4 + l4) ^ (arow & 7)) << 3)];
        }
        #pragma unroll
        for (int ni = 0; ni < 2; ++ni) {
            int brow = wc * 32 + ni * 16 + l16;
            #pragma unroll
            for (int ks = 0; ks < 2; ++ks)
                bv[ni][ks] = *(const bf16x8*)&Bs[buf * 4096 + brow * 64 + (((ks * 4 + l4) ^ (brow & 7)) << 3)];
        }
        #pragma unroll
        for (int ks = 0; ks < 2; ++ks)
            #pragma unroll
            for (int mi = 0; mi < 2; ++mi)
                #pragma unroll
                for (int ni = 0; ni < 2; ++ni)
                    acc[mi][ni] = __builtin_amdgcn_mfma_f32_16x16x32_bf16(af[mi][ks], bv[ni][ks], acc[mi][ni], 0, 0, 0);
    };

    loadRegs(0);
    writeLDS(0);
    __syncthreads();
    int cur = 0;
    #pragma unroll
    for (int it = 0; it < 3; ++it) {       // K=256 -> 4 steps
        loadRegs(it + 1);
        compute(cur);
        writeLDS(cur ^ 1);
        __syncthreads();
        cur ^= 1;
    }
    compute(cur);

    __syncthreads();
    float* sc = (float*)shmem;             // 64x64 f32 = 16KB
    #pragma unroll
    for (int mi = 0; mi < 2; ++mi)
        #pragma unroll
        for (int ni = 0; ni < 2; ++ni)
            #pragma unroll
            for (int e = 0; e < 4; ++e)
                sc[(wr * 32 + mi * 16 + l4 * 4 + e) * 64 + wc * 32 + ni * 16 + l16] = acc[mi][ni][e];
    __syncthreads();
    const int r2 = t >> 2, c0 = (t & 3) * 16;
    const float* arow = alpha + (size_t)(bm0 + r2) * N_POOL;
    __align__(16) ushort_t u[16];
    #pragma unroll
    for (int j = 0; j < 16; ++j)
        u[j] = bfb(sc[r2 * 64 + c0 + j] * arow[(bn0 + c0 + j) >> 2]);
    ushort_t* dst = Xu + (size_t)(bm0 + r2) * LDA_X + bn0 + c0;
    *(uint4*)dst = ((uint4*)u)[0];
    *(uint4*)(dst + 8) = ((uint4*)u)[1];
}

// ================= kB: GEMM2 64x64, splitK x8 uneven, bf16 partials (R9) =================
__global__ __launch_bounds__(256) void kB(const ushort_t* __restrict__ Xu,
                                          const ushort_t* __restrict__ Mt,
                                          ushort_t* __restrict__ part) {
    __shared__ __align__(16) ushort_t As[2][4096];
    __shared__ __align__(16) ushort_t Bs[2][4096];
    const int t = threadIdx.x;
    const int w = t >> 6, l = t & 63, l16 = l & 15, l4 = l >> 4;
    const int wr = w >> 1, wc = w & 1;
    const int bm0 = blockIdx.x * 64, bn0 = blockIdx.y * 64;
    const int z = blockIdx.z;
    const int steps = (z < 4) ? 6 : 5;
    const int kc0 = (z < 4) ? z * 384 : 1536 + (z - 4) * 320;
    const int srow = t >> 3;
    const int schunk = (t & 7) ^ (srow & 7);   // source-side swizzle (rule #21)

    f32x4 acc[2][2];
    #pragma unroll
    for (int i = 0; i < 2; ++i)
        #pragma unroll
        for (int j = 0; j < 2; ++j) acc[i][j] = (f32x4){0.f, 0.f, 0.f, 0.f};

    auto stage = [&](int buf, int k0) {
        #pragma unroll
        for (int h = 0; h < 2; ++h) {
            gld16(Xu + (size_t)(bm0 + srow + h * 32) * LDA_X + k0 + schunk * 8,
                  &As[buf][h * 2048 + w * 512]);
            gld16(Mt + (size_t)(bn0 + srow + h * 32) * LDA_X + k0 + schunk * 8,
                  &Bs[buf][h * 2048 + w * 512]);
        }
    };
    auto compute = [&](int buf) {
        bf16x8 af[2][2], bv[2][2];
        #pragma unroll
        for (int mi = 0; mi < 2; ++mi) {
            int arow = wr * 32 + mi * 16 + l16;
            #pragma unroll
            for (int ks = 0; ks < 2; ++ks)
                af[mi][ks] = *(const bf16x8*)&As[buf][arow * 64 + (((ks * 4 + l4) ^ (arow & 7)) << 3)];
        }
        #pragma unroll
        for (int ni = 0; ni < 2; ++ni) {
            int brow = wc * 32 + ni * 16 + l16;
            #pragma unroll
            for (int ks = 0; ks < 2; ++ks)
                bv[ni][ks] = *(const bf16x8*)&Bs[buf][brow * 64 + (((ks * 4 + l4) ^ (brow & 7)) << 3)];
        }
        #pragma unroll
        for (int ks = 0; ks < 2; ++ks)
            #pragma unroll
            for (int mi = 0; mi < 2; ++mi)
                #pragma unroll
                for (int ni = 0; ni < 2; ++ni)
                    acc[mi][ni] = __builtin_amdgcn_mfma_f32_16x16x32_bf16(af[mi][ks], bv[ni][ks], acc[mi][ni], 0, 0, 0);
    };

    stage(0, kc0);
    __syncthreads();
    int cur = 0;
    for (int it = 0; it < steps - 1; ++it) {
        stage(cur ^ 1, kc0 + (it + 1) * 64);
        compute(cur);
        __syncthreads();
        cur ^= 1;
    }
    compute(cur);

    // epilogue: acc -> LDS f32 -> bf16, 2x16B stores/thread
    __syncthreads();
    float* sc = (float*)&As[0][0];
    #pragma unroll
    for (int mi = 0; mi < 2; ++mi)
        #pragma unroll
        for (int ni = 0; ni < 2; ++ni)
            #pragma unroll
            for (int e = 0; e < 4; ++e)
                sc[(wr * 32 + mi * 16 + l4 * 4 + e) * 64 + wc * 32 + ni * 16 + l16] = acc[mi][ni][e];
    __syncthreads();
    const int r2 = t >> 2, c0 = (t & 3) * 16;
    __align__(16) ushort_t u[16];
    #pragma unroll
    for (int j = 0; j < 16; ++j) u[j] = bfb(sc[r2 * 64 + c0 + j]);
    ushort_t* P = part + (size_t)z * (2048 * 256) + (size_t)(bm0 + r2) * 256 + bn0 + c0;
    *(uint4*)P = ((uint4*)u)[0];
    *(uint4*)(P + 8) = ((uint4*)u)[1];
}

// ================= kC: sum 8 bf16 partials + b_base; residual; LN =================
__global__ __launch_bounds__(256) void kC(const ushort_t* __restrict__ part,
                                          const float* __restrict__ hA,
                                          const float* __restrict__ bb,
                                          const float* __restrict__ gamma_p,
                                          const float* __restrict__ lns,
                                          const float* __restrict__ lnb,
                                          float* __restrict__ out) {
    const int wave = threadIdx.x >> 6;
    const int lane = threadIdx.x & 63;
    const int b = blockIdx.x * 4 + wave;
    const float g = gamma_p[0];
    const size_t base = (size_t)b * 256 + lane * 4;

    float p0 = 0.f, p1 = 0.f, p2 = 0.f, p3 = 0.f;
    #pragma unroll
    for (int z = 0; z < 8; ++z) {
        ushort4 q = *(const ushort4*)&part[(size_t)z * 2048 * 256 + base];
        p0 += bf2f(q.x); p1 += bf2f(q.y); p2 += bf2f(q.z); p3 += bf2f(q.w);
    }
    float4 h  = *(const float4*)&hA[base];
    float4 b4 = *(const float4*)&bb[lane * 4];
    float y0 = h.x + g * (p0 + b4.x);
    float y1 = h.y + g * (p1 + b4.y);
    float y2 = h.z + g * (p2 + b4.z);
    float y3 = h.w + g * (p3 + b4.w);

    float sum = y0 + y1 + y2 + y3;
    float ss  = y0*y0 + y1*y1 + y2*y2 + y3*y3;
    #pragma unroll
    for (int off = 1; off < 64; off <<= 1) {
        sum += __shfl_xor(sum, off);
        ss  += __shfl_xor(ss, off);
    }
    float mu  = sum * (1.0f / 256.0f);
    float var = ss * (1.0f / 256.0f) - mu * mu;
    float inv = rsqrtf(var + 1e-5f);

    float4 sc = *(const float4*)&lns[lane * 4];
    float4 bi = *(const float4*)&lnb[lane * 4];
    float4 o;
    o.x = (y0 - mu) * inv * sc.x + bi.x;
    o.y = (y1 - mu) * inv * sc.y + bi.y;
    o.z = (y2 - mu) * inv * sc.z + bi.z;
    o.w = (y3 - mu) * inv * sc.w + bi.w;
    *(float4*)&out[base] = o;
}

extern "C" void kernel_launch(void* const* d_in, const int* in_sizes, int n_in,
                              void* d_out, int out_size, void* d_ws, size_t ws_size,
                              hipStream_t stream) {
    const float* hA    = (const float*)d_in[0];
    const float* pool  = (const float*)d_in[1];
    const float* alpha = (const float*)d_in[2];
    const float* Wb    = (const float*)d_in[3];
    const float* bb    = (const float*)d_in[4];
    const float* gamma = (const float*)d_in[5];
    const float* lns   = (const float*)d_in[6];
    const float* lnb   = (const float*)d_in[7];
    float* out = (float*)d_out;

    ushort_t* Xu   = (ushort_t*)d_ws;                  // [2048][2816] bf16
    ushort_t* Mt   = Xu + (size_t)2048 * LDA_X;        // [256][2816]  bf16
    ushort_t* part = Mt + (size_t)256 * LDA_X;         // [8][2048][256] bf16

    kFront<<<3168, 256, 0, stream>>>(hA, pool, alpha, Wb, Xu, Mt);
    kB<<<dim3(32, 4, 8), 256, 0, stream>>>(Xu, Mt, part);   // measurement: kB twice
    kB<<<dim3(32, 4, 8), 256, 0, stream>>>(Xu, Mt, part);   // (idempotent, pure)
    kC<<<512, 256, 0, stream>>>(part, hA, bb, gamma, lns, lnb, out);
}

// Round 12
// 30.361 us; speedup vs baseline: 1.2478x; 1.2478x over previous
//
#include <hip/hip_runtime.h>
#include <hip/hip_bf16.h>

// R12: single change vs R9 — kB XCD-locality swizzle.
//   kB grid flattened to 1024 1-D; z = bid&7, n = (bid>>3)&3, m = bid>>5.
//   With round-robin bid%8 -> XCD placement, all blocks of split-slice z land on
//   XCD z: X z-slice (1.44MB) + Mt z-slice (180KB) read ONCE into that L2;
//   4 blocks/CU balanced; part z-plane written locally. Cold X traffic 46->11.5MB.
// LEDGER (R11 measurement): F(fixed/replay)~9.6us, kFront~6, kB_cold~12(warm 7.3),
//   kC~3. This round targets kB's cold-read penalty.
// Pipeline unchanged otherwise: kFront (GEMM1 reg-staged + prep packed) ->
//   kB (GEMM2 64x64 splitK x8 uneven, bf16 partials) -> kC (sum8 + LN).

typedef __attribute__((ext_vector_type(8))) short bf16x8;
typedef __attribute__((ext_vector_type(4))) float f32x4;
typedef unsigned short ushort_t;

#define LDA_X 2816
#define N_POOL 512
#define D_POOL 4096

__device__ __forceinline__ void gld16(const ushort_t* g, ushort_t* l) {
    __builtin_amdgcn_global_load_lds((__attribute__((address_space(1))) void*)g,
                                     (__attribute__((address_space(3))) void*)l, 16, 0, 0);
}

__device__ __forceinline__ ushort_t bfb(float x) {
    union { __hip_bfloat16 h; ushort_t u; } c; c.h = __float2bfloat16(x); return c.u;
}

__device__ __forceinline__ float bf2f(ushort_t u) {
    union { unsigned int i; float f; } c; c.i = ((unsigned int)u) << 16; return c.f;
}

__device__ __forceinline__ void write4(ushort_t* p, float4 v) {
    ushort4 w = {bfb(v.x), bfb(v.y), bfb(v.z), bfb(v.w)};
    *(ushort4*)p = w;
}

// ================= kFront: GEMM1 (0..1023) + prep (1024..3167) =================
__global__ __launch_bounds__(256) void kFront(const float* __restrict__ hA,
                                              const float* __restrict__ pool,
                                              const float* __restrict__ alpha,
                                              const float* __restrict__ Wb,
                                              ushort_t* __restrict__ Xu,
                                              ushort_t* __restrict__ Mt) {
    __shared__ __align__(16) ushort_t shmem[16384];   // 32KB pool
    ushort_t* As = shmem;                             // [2][4096]
    ushort_t* Bs = shmem + 8192;
    const int t = threadIdx.x;
    const int bid = blockIdx.x;

    if (bid >= 1024) {  // ---------------- prep path ----------------
        const int b2 = bid - 1024;
        if (b2 < 512) {                    // X hA seg [2048][256]
            int idx = b2 * 256 + t, b = idx >> 6, a4 = (idx & 63) << 2;
            write4(Xu + (size_t)b * LDA_X + 2048 + a4, *(const float4*)&hA[(size_t)b * 256 + a4]);
        } else if (b2 < 1536) {            // X alpha seg [2048][512]
            int idx = (b2 - 512) * 256 + t, b = idx >> 7, j4 = (idx & 127) << 2;
            write4(Xu + (size_t)b * LDA_X + 2304 + j4, *(const float4*)&alpha[(size_t)b * 512 + j4]);
        } else if (b2 < 2048) {            // Mt U: [c][4n..] = pool[n][4c..]
            int idx = (b2 - 1536) * 256 + t, c = idx >> 9, n = idx & 511;
            write4(Mt + (size_t)c * LDA_X + (n << 2), *(const float4*)&pool[(size_t)n * D_POOL + (c << 2)]);
        } else if (b2 < 2112) {            // Mt Wb: [c][2048+q]
            int idx = (b2 - 2048) * 256 + t, c = idx >> 6, q = (idx & 63) << 2;
            write4(Mt + (size_t)c * LDA_X + 2048 + q, *(const float4*)&Wb[(size_t)c * 256 + q]);
        } else {                           // Mt bias via 64x64 LDS transpose
            float* Lf = (float*)shmem;     // [64][65] f32 = 16.6KB
            int tb = b2 - 2112;            // 0..31
            int j0 = (tb >> 2) * 64, c0t = (tb & 3) * 64;
            #pragma unroll
            for (int i = 0; i < 16; ++i) {
                int idx = i * 256 + t, jj = idx >> 6, cc = idx & 63;
                Lf[jj * 65 + cc] = pool[(size_t)(j0 + jj) * D_POOL + 2048 + c0t + cc];
            }
            __syncthreads();
            int cc = t >> 2, js = (t & 3) * 16;
            __align__(16) ushort_t u[16];
            #pragma unroll
            for (int j = 0; j < 16; ++j) u[j] = bfb(Lf[(js + j) * 65 + cc]);
            ushort_t* dst = Mt + (size_t)(c0t + cc) * LDA_X + 2304 + j0 + js;
            *(uint4*)dst = ((uint4*)u)[0];
            *(uint4*)(dst + 8) = ((uint4*)u)[1];
        }
        return;
    }

    // ---------------- GEMM1 path (reg-staged, verified) ----------------
    const int w = t >> 6, l = t & 63, l16 = l & 15, l4 = l >> 4;
    const int wr = w >> 1, wc = w & 1;
    const int bm0 = (bid >> 5) * 64, bn0 = (bid & 31) * 64;
    const int row = t >> 2, cs = t & 3;

    f32x4 acc[2][2];
    #pragma unroll
    for (int i = 0; i < 2; ++i)
        #pragma unroll
        for (int j = 0; j < 2; ++j) acc[i][j] = (f32x4){0.f, 0.f, 0.f, 0.f};

    float4 aR[4], bR[4];
    const int kk = bn0 + row;
    const float* bbase = pool + (size_t)(kk >> 2) * D_POOL + 1024 + (kk & 3) * 256;
    const float* abase = hA + (size_t)(bm0 + row) * 256;

    auto loadRegs = [&](int step) {
        const int a0 = step * 64;
        #pragma unroll
        for (int p = 0; p < 4; ++p) {
            int c0 = (cs + p * 4) << 2;
            aR[p] = *(const float4*)(abase + a0 + c0);
            bR[p] = *(const float4*)(bbase + a0 + c0);
        }
    };
    auto writeLDS = [&](int buf) {
        #pragma unroll
        for (int p = 0; p < 4; ++p) {
            int c0 = (cs + p * 4) << 2;
            int off = row * 64 + (((c0 >> 3) ^ (row & 7)) << 3) + ((c0 >> 2) & 1) * 4;
            ushort4 ua = {bfb(aR[p].x), bfb(aR[p].y), bfb(aR[p].z), bfb(aR[p].w)};
            ushort4 ub = {bfb(bR[p].x), bfb(bR[p].y), bfb(bR[p].z), bfb(bR[p].w)};
            *(ushort4*)&As[buf * 4096 + off] = ua;
            *(ushort4*)&Bs[buf * 4096 + off] = ub;
        }
    };
    auto compute = [&](int buf) {
        bf16x8 af[2][2], bv[2][2];
        #pragma unroll
        for (int mi = 0; mi < 2; ++mi) {
            int arow = wr * 32 + mi * 16 + l16;
            #pragma unroll
            for (int ks = 0; ks < 2; ++ks)
                af[mi][ks] = *(const bf16x8*)&As[buf * 4096 + arow * 64 + (((ks * 4 + l4) ^ (arow & 7)) << 3)];
        }
        #pragma unroll
        for (int ni = 0; ni < 2; ++ni) {
            int brow = wc * 32 + ni * 16 + l16;
            #pragma unroll
            for (int ks = 0; ks < 2; ++ks)
                bv[ni][ks] = *(const bf16x8*)&Bs[buf * 4096 + brow * 64 + (((ks * 4 + l4) ^ (brow & 7)) << 3)];
        }
        #pragma unroll
        for (int ks = 0; ks < 2; ++ks)
            #pragma unroll
            for (int mi = 0; mi < 2; ++mi)
                #pragma unroll
                for (int ni = 0; ni < 2; ++ni)
                    acc[mi][ni] = __builtin_amdgcn_mfma_f32_16x16x32_bf16(af[mi][ks], bv[ni][ks], acc[mi][ni], 0, 0, 0);
    };

    loadRegs(0);
    writeLDS(0);
    __syncthreads();
    int cur = 0;
    #pragma unroll
    for (int it = 0; it < 3; ++it) {       // K=256 -> 4 steps
        loadRegs(it + 1);
        compute(cur);
        writeLDS(cur ^ 1);
        __syncthreads();
        cur ^= 1;
    }
    compute(cur);

    __syncthreads();
    float* sc = (float*)shmem;             // 64x64 f32 = 16KB
    #pragma unroll
    for (int mi = 0; mi < 2; ++mi)
        #pragma unroll
        for (int ni = 0; ni < 2; ++ni)
            #pragma unroll
            for (int e = 0; e < 4; ++e)
                sc[(wr * 32 + mi * 16 + l4 * 4 + e) * 64 + wc * 32 + ni * 16 + l16] = acc[mi][ni][e];
    __syncthreads();
    const int r2 = t >> 2, c0 = (t & 3) * 16;
    const float* arow = alpha + (size_t)(bm0 + r2) * N_POOL;
    __align__(16) ushort_t u[16];
    #pragma unroll
    for (int j = 0; j < 16; ++j)
        u[j] = bfb(sc[r2 * 64 + c0 + j] * arow[(bn0 + c0 + j) >> 2]);
    ushort_t* dst = Xu + (size_t)(bm0 + r2) * LDA_X + bn0 + c0;
    *(uint4*)dst = ((uint4*)u)[0];
    *(uint4*)(dst + 8) = ((uint4*)u)[1];
}

// ================= kB: GEMM2 64x64, splitK x8, XCD-locality mapping =================
__global__ __launch_bounds__(256) void kB(const ushort_t* __restrict__ Xu,
                                          const ushort_t* __restrict__ Mt,
                                          ushort_t* __restrict__ part) {
    __shared__ __align__(16) ushort_t As[2][4096];
    __shared__ __align__(16) ushort_t Bs[2][4096];
    const int t = threadIdx.x;
    const int w = t >> 6, l = t & 63, l16 = l & 15, l4 = l >> 4;
    const int wr = w >> 1, wc = w & 1;
    // XCD-locality: z = bid&7 -> with round-robin bid%8 XCD placement, all blocks
    // of split-slice z share one XCD; its X/Mt K-slice is read once into that L2.
    const int bid = blockIdx.x;                // 0..1023
    const int z = bid & 7;
    const int n = (bid >> 3) & 3;
    const int m = bid >> 5;
    const int bm0 = m * 64, bn0 = n * 64;
    const int steps = (z < 4) ? 6 : 5;
    const int kc0 = (z < 4) ? z * 384 : 1536 + (z - 4) * 320;
    const int srow = t >> 3;
    const int schunk = (t & 7) ^ (srow & 7);   // source-side swizzle (rule #21)

    f32x4 acc[2][2];
    #pragma unroll
    for (int i = 0; i < 2; ++i)
        #pragma unroll
        for (int j = 0; j < 2; ++j) acc[i][j] = (f32x4){0.f, 0.f, 0.f, 0.f};

    auto stage = [&](int buf, int k0) {
        #pragma unroll
        for (int h = 0; h < 2; ++h) {
            gld16(Xu + (size_t)(bm0 + srow + h * 32) * LDA_X + k0 + schunk * 8,
                  &As[buf][h * 2048 + w * 512]);
            gld16(Mt + (size_t)(bn0 + srow + h * 32) * LDA_X + k0 + schunk * 8,
                  &Bs[buf][h * 2048 + w * 512]);
        }
    };
    auto compute = [&](int buf) {
        bf16x8 af[2][2], bv[2][2];
        #pragma unroll
        for (int mi = 0; mi < 2; ++mi) {
            int arow = wr * 32 + mi * 16 + l16;
            #pragma unroll
            for (int ks = 0; ks < 2; ++ks)
                af[mi][ks] = *(const bf16x8*)&As[buf][arow * 64 + (((ks * 4 + l4) ^ (arow & 7)) << 3)];
        }
        #pragma unroll
        for (int ni = 0; ni < 2; ++ni) {
            int brow = wc * 32 + ni * 16 + l16;
            #pragma unroll
            for (int ks = 0; ks < 2; ++ks)
                bv[ni][ks] = *(const bf16x8*)&Bs[buf][brow * 64 + (((ks * 4 + l4) ^ (brow & 7)) << 3)];
        }
        #pragma unroll
        for (int ks = 0; ks < 2; ++ks)
            #pragma unroll
            for (int mi = 0; mi < 2; ++mi)
                #pragma unroll
                for (int ni = 0; ni < 2; ++ni)
                    acc[mi][ni] = __builtin_amdgcn_mfma_f32_16x16x32_bf16(af[mi][ks], bv[ni][ks], acc[mi][ni], 0, 0, 0);
    };

    stage(0, kc0);
    __syncthreads();
    int cur = 0;
    for (int it = 0; it < steps - 1; ++it) {
        stage(cur ^ 1, kc0 + (it + 1) * 64);
        compute(cur);
        __syncthreads();
        cur ^= 1;
    }
    compute(cur);

    // epilogue: acc -> LDS f32 -> bf16, 2x16B stores/thread
    __syncthreads();
    float* sc = (float*)&As[0][0];
    #pragma unroll
    for (int mi = 0; mi < 2; ++mi)
        #pragma unroll
        for (int ni = 0; ni < 2; ++ni)
            #pragma unroll
            for (int e = 0; e < 4; ++e)
                sc[(wr * 32 + mi * 16 + l4 * 4 + e) * 64 + wc * 32 + ni * 16 + l16] = acc[mi][ni][e];
    __syncthreads();
    const int r2 = t >> 2, c0 = (t & 3) * 16;
    __align__(16) ushort_t u[16];
    #pragma unroll
    for (int j = 0; j < 16; ++j) u[j] = bfb(sc[r2 * 64 + c0 + j]);
    ushort_t* P = part + (size_t)z * (2048 * 256) + (size_t)(bm0 + r2) * 256 + bn0 + c0;
    *(uint4*)P = ((uint4*)u)[0];
    *(uint4*)(P + 8) = ((uint4*)u)[1];
}

// ================= kC: sum 8 bf16 partials + b_base; residual; LN =================
__global__ __launch_bounds__(256) void kC(const ushort_t* __restrict__ part,
                                          const float* __restrict__ hA,
                                          const float* __restrict__ bb,
                                          const float* __restrict__ gamma_p,
                                          const float* __restrict__ lns,
                                          const float* __restrict__ lnb,
                                          float* __restrict__ out) {
    const int wave = threadIdx.x >> 6;
    const int lane = threadIdx.x & 63;
    const int b = blockIdx.x * 4 + wave;
    const float g = gamma_p[0];
    const size_t base = (size_t)b * 256 + lane * 4;

    float p0 = 0.f, p1 = 0.f, p2 = 0.f, p3 = 0.f;
    #pragma unroll
    for (int z = 0; z < 8; ++z) {
        ushort4 q = *(const ushort4*)&part[(size_t)z * 2048 * 256 + base];
        p0 += bf2f(q.x); p1 += bf2f(q.y); p2 += bf2f(q.z); p3 += bf2f(q.w);
    }
    float4 h  = *(const float4*)&hA[base];
    float4 b4 = *(const float4*)&bb[lane * 4];
    float y0 = h.x + g * (p0 + b4.x);
    float y1 = h.y + g * (p1 + b4.y);
    float y2 = h.z + g * (p2 + b4.z);
    float y3 = h.w + g * (p3 + b4.w);

    float sum = y0 + y1 + y2 + y3;
    float ss  = y0*y0 + y1*y1 + y2*y2 + y3*y3;
    #pragma unroll
    for (int off = 1; off < 64; off <<= 1) {
        sum += __shfl_xor(sum, off);
        ss  += __shfl_xor(ss, off);
    }
    float mu  = sum * (1.0f / 256.0f);
    float var = ss * (1.0f / 256.0f) - mu * mu;
    float inv = rsqrtf(var + 1e-5f);

    float4 sc = *(const float4*)&lns[lane * 4];
    float4 bi = *(const float4*)&lnb[lane * 4];
    float4 o;
    o.x = (y0 - mu) * inv * sc.x + bi.x;
    o.y = (y1 - mu) * inv * sc.y + bi.y;
    o.z = (y2 - mu) * inv * sc.z + bi.z;
    o.w = (y3 - mu) * inv * sc.w + bi.w;
    *(float4*)&out[base] = o;
}

extern "C" void kernel_launch(void* const* d_in, const int* in_sizes, int n_in,
                              void* d_out, int out_size, void* d_ws, size_t ws_size,
                              hipStream_t stream) {
    const float* hA    = (const float*)d_in[0];
    const float* pool  = (const float*)d_in[1];
    const float* alpha = (const float*)d_in[2];
    const float* Wb    = (const float*)d_in[3];
    const float* bb    = (const float*)d_in[4];
    const float* gamma = (const float*)d_in[5];
    const float* lns   = (const float*)d_in[6];
    const float* lnb   = (const float*)d_in[7];
    float* out = (float*)d_out;

    ushort_t* Xu   = (ushort_t*)d_ws;                  // [2048][2816] bf16
    ushort_t* Mt   = Xu + (size_t)2048 * LDA_X;        // [256][2816]  bf16
    ushort_t* part = Mt + (size_t)256 * LDA_X;         // [8][2048][256] bf16

    kFront<<<3168, 256, 0, stream>>>(hA, pool, alpha, Wb, Xu, Mt);
    kB<<<1024, 256, 0, stream>>>(Xu, Mt, part);
    kC<<<512, 256, 0, stream>>>(part, hA, bb, gamma, lns, lnb, out);
}